// Round 5
// baseline (34.533 us; speedup 1.0000x reference)
//
#include <hip/hip_runtime.h>
#include <hip/hip_bf16.h>
#include <cstdint>

// LearnableUpsamplingLayer: polyphase decomposition + bf16 MFMA.
// B=8, T=16384, C=64, F=64, filter=5, leaky 0.3.
// out[b,2t+p,f] = sum_tap M_p[tap][c,f] * x[t-1+tap, c]   (x outside [0,T) = 0)
// Even p=0: 3 taps; odd p=1: 4 taps. Frames 0,1 get a precomputed correction
// (the polyphase substitution leaks a (1-w)*x[0] term through blend[-1]).
//
// R5: operand swap. D = W_tile (A, M=16 filters) x X (B, N=16 time-pairs).
// A/B fragment layouts are mutual transposes, so the packed weight table and
// the LDS x-reads are BIT-IDENTICAL to the previous A=x scheme; only the C/D
// interpretation flips: each thread now owns 4 CONSECUTIVE FILTERS of one
// frame -> epilogue is 2 global_store_dwordx4 per window (was 8 scattered
// dword stores). Independent waves, no barriers, 4 windows per wave.

#define T_ 16384
#define TWO_T 32768
#define XSTRIDE 72         // ushorts per frame row (144B; benign 2-way alias)
#define WSL 1376           // ushorts per wave slice (19*72=1368, pad to 16B)

typedef __bf16 bf16x8 __attribute__((ext_vector_type(8)));
typedef __bf16 bf16x4 __attribute__((ext_vector_type(4)));
typedef float  f32x4  __attribute__((ext_vector_type(4)));
typedef unsigned short u16x8 __attribute__((ext_vector_type(8)));

__device__ __forceinline__ float sigmoidf_(float z) {
    return 1.0f / (1.0f + expf(-z));
}

__device__ __forceinline__ unsigned short f2bf(float f) {
    union { float f; uint32_t u; } v; v.f = f;
    uint32_t u = v.u;
    return (unsigned short)((u + 0x7FFFu + ((u >> 16) & 1u)) >> 16);
}

// ---------------- prep: 64 blocks x 64 threads (unchanged layout).
// Blocks 0..55: the 7 polyphase matrices as packed bf16 fragments:
//   frag (phase, ks, nt): lane l elem i = M[tap=ks>>1][c=(ks&1)*32+(l>>4)*8+i]
//                                          [f=nt*16+(l&15)]
//   (serves as the A-fragment of W^T: row=f=l&15, k=c=(l>>4)*8+i)
// Blocks 56..63: b = fi-56; corr[b][{E,O}][f] = sum_c K[{1,0}][c][f]*(1-w_c)*x[b,0,c]
__global__ void lu_prep_kernel(const float* __restrict__ iw,
                               const float* __restrict__ ck,
                               const float* __restrict__ x,
                               unsigned short* __restrict__ bp,
                               float* __restrict__ corrf) {
    int fi = blockIdx.x;
    int l  = threadIdx.x;
    if (fi < 56) {
        int phase, ks, nt;
        if (fi < 24) { phase = 0; ks = fi >> 2; nt = fi & 3; }
        else         { phase = 1; ks = (fi - 24) >> 2; nt = (fi - 24) & 3; }
        int tap = ks >> 1;
        int n   = nt * 16 + (l & 15);
        int c0  = ((ks & 1) << 5) + ((l >> 4) << 3);
        u16x8 pk;
#pragma unroll
        for (int i = 0; i < 8; ++i) {
            int c = c0 + i;
            float w = sigmoidf_(iw[c]);
            float v;
            #define CK(k) ck[((k) * 64 + c) * 64 + n]
            if (phase == 0) {
                if (tap == 0)      v = CK(0) + w * CK(1);
                else if (tap == 1) v = (1.f - w) * CK(1) + CK(2) + w * CK(3);
                else               v = (1.f - w) * CK(3) + CK(4);
            } else {
                if (tap == 0)      v = w * CK(0);
                else if (tap == 1) v = (1.f - w) * CK(0) + CK(1) + w * CK(2);
                else if (tap == 2) v = (1.f - w) * CK(2) + CK(3) + w * CK(4);
                else               v = (1.f - w) * CK(4);
            }
            #undef CK
            pk[i] = f2bf(v);
        }
        *(u16x8*)(bp + (((size_t)fi * 64) + l) * 8) = pk;
    } else {
        int b = fi - 56;
        int f = l;
        float cE = 0.f, cO = 0.f;
#pragma unroll
        for (int c = 0; c < 64; ++c) {
            float w = sigmoidf_(iw[c]);
            float g = (1.f - w) * x[(size_t)b * T_ * 64 + c];
            cE += ck[(64 + c) * 64 + f] * g;   // K1
            cO += ck[c * 64 + f] * g;          // K0
        }
        corrf[b * 128 + f]      = cE;
        corrf[b * 128 + 64 + f] = cO;
    }
}

// ---------------- main ----------------
__device__ __forceinline__ void issue_loads(const float* __restrict__ x,
                                            int b, int t0, int lane, float4* ld) {
#pragma unroll
    for (int it = 0; it < 5; ++it) {
        int idx = it * 64 + lane;       // 0..319, need 304
        int j   = idx >> 4;             // frame 0..18
        int c4  = (idx & 15) << 2;
        int gf  = t0 - 1 + j;
        float4 v = make_float4(0.f, 0.f, 0.f, 0.f);
        if (idx < 304 && gf >= 0 && gf < T_)
            v = *(const float4*)(x + ((size_t)b * T_ + gf) * 64 + c4);
        ld[it] = v;
    }
}

__global__ __launch_bounds__(256, 4) void lu_main_kernel(
        const float* __restrict__ x,
        const unsigned short* __restrict__ bp,
        const float* __restrict__ corrf,
        const float* __restrict__ bias,
        float* __restrict__ out) {
    __shared__ __align__(16) unsigned short xl[4][WSL];   // 11,008 B

    const int bid  = blockIdx.x;        // 0..2047: (batch, quad)
    const int b    = bid >> 8;
    const int p0   = (bid & 255) << 6;  // first time-pair of this quad (64 pairs)
    const int tid  = threadIdx.x;
    const int lane = tid & 63;
    const int wv   = tid >> 6;          // wave = filter tile

    unsigned short* xw = &xl[wv][0];

    // ---- prefetch window 0 ----
    float4 ld[5];
    issue_loads(x, b, p0, lane, ld);

    // ---- weight A-fragments for this wave's filter tile (loaded once) ----
    bf16x8 We[6], Wo[8];
#pragma unroll
    for (int ks = 0; ks < 6; ++ks)
        We[ks] = __builtin_bit_cast(bf16x8,
            *(const u16x8*)(bp + (((size_t)(ks * 4 + wv)) * 64 + lane) * 8));
#pragma unroll
    for (int ks = 0; ks < 8; ++ks)
        Wo[ks] = __builtin_bit_cast(bf16x8,
            *(const u16x8*)(bp + (((size_t)(24 + ks * 4 + wv)) * 64 + lane) * 8));

    const int hi  = lane >> 4;
    const int col = lane & 15;          // time-pair within window
    // this thread's 4 consecutive filters: wv*16 + 4*hi + {0..3}
    const float4 bias4 = *(const float4*)(bias + (wv << 4) + (hi << 2));

    for (int w = 0; w < 4; ++w) {
        const int t0 = p0 + (w << 4);

        // ---- cvt + ds_write window w (native bf16 casts -> cvt_pk) ----
#pragma unroll
        for (int it = 0; it < 5; ++it) {
            int idx = it * 64 + lane;
            if (idx < 304) {
                int j  = idx >> 4;
                int c4 = (idx & 15) << 2;
                bf16x4 pk;
                pk[0] = (__bf16)ld[it].x; pk[1] = (__bf16)ld[it].y;
                pk[2] = (__bf16)ld[it].z; pk[3] = (__bf16)ld[it].w;
                *(bf16x4*)(xw + j * XSTRIDE + c4) = pk;
            }
        }

        // ---- prefetch window w+1 (in flight across compute below) ----
        if (w < 3) issue_loads(x, b, p0 + ((w + 1) << 4), lane, ld);

        // ---- B reads (x) interleaved with 14 MFMA (E and O share B-frags) ----
        // B-frag lane l elem i = x[t0-1 + col + tap][(ks&1)*32 + hi*8 + i]
        // == the same ds_read_b128 as the old A-fragment.
        f32x4 accE = {0.f, 0.f, 0.f, 0.f};
        f32x4 accO = {0.f, 0.f, 0.f, 0.f};
#pragma unroll
        for (int tap = 0; tap < 4; ++tap)
#pragma unroll
            for (int h = 0; h < 2; ++h) {
                bf16x8 xb = __builtin_bit_cast(bf16x8,
                    *(const u16x8*)(xw + (col + tap) * XSTRIDE + (h << 5) + (hi << 3)));
                int ks = tap * 2 + h;
                if (tap < 3)
                    accE = __builtin_amdgcn_mfma_f32_16x16x32_bf16(We[ks], xb, accE, 0, 0, 0);
                accO = __builtin_amdgcn_mfma_f32_16x16x32_bf16(Wo[ks], xb, accO, 0, 0, 0);
            }

        // ---- boundary correction (output frames 0,1 of each batch) ----
        if (((bid & 255) | w) == 0 && col == 0) {
            const float4 cE4 = *(const float4*)(corrf + b * 128 + (wv << 4) + (hi << 2));
            const float4 cO4 = *(const float4*)(corrf + b * 128 + 64 + (wv << 4) + (hi << 2));
            accE[0] -= cE4.x; accE[1] -= cE4.y; accE[2] -= cE4.z; accE[3] -= cE4.w;
            accO[0] -= cO4.x; accO[1] -= cO4.y; accO[2] -= cO4.z; accO[3] -= cO4.w;
        }

        // ---- epilogue: bias + leaky_relu, one dwordx4 store per phase ----
        const int tl = t0 + col;                       // time-pair index
        const size_t fbase = ((size_t)b * TWO_T + ((size_t)tl << 1)) * 64
                           + (wv << 4) + (hi << 2);
        float4 vE, vO;
        {
            float e0 = accE[0] + bias4.x, e1 = accE[1] + bias4.y,
                  e2 = accE[2] + bias4.z, e3 = accE[3] + bias4.w;
            vE.x = e0 >= 0.f ? e0 : 0.3f * e0;
            vE.y = e1 >= 0.f ? e1 : 0.3f * e1;
            vE.z = e2 >= 0.f ? e2 : 0.3f * e2;
            vE.w = e3 >= 0.f ? e3 : 0.3f * e3;
            float o0 = accO[0] + bias4.x, o1 = accO[1] + bias4.y,
                  o2 = accO[2] + bias4.z, o3 = accO[3] + bias4.w;
            vO.x = o0 >= 0.f ? o0 : 0.3f * o0;
            vO.y = o1 >= 0.f ? o1 : 0.3f * o1;
            vO.z = o2 >= 0.f ? o2 : 0.3f * o2;
            vO.w = o3 >= 0.f ? o3 : 0.3f * o3;
        }
        *(float4*)(out + fbase)      = vE;   // even frame 2*tl
        *(float4*)(out + fbase + 64) = vO;   // odd frame 2*tl+1
    }
}

extern "C" void kernel_launch(void* const* d_in, const int* in_sizes, int n_in,
                              void* d_out, int out_size, void* d_ws, size_t ws_size,
                              hipStream_t stream) {
    (void)in_sizes; (void)n_in; (void)out_size; (void)ws_size;
    const float* x    = (const float*)d_in[0];
    const float* iw   = (const float*)d_in[1];
    const float* ck   = (const float*)d_in[2];
    const float* bias = (const float*)d_in[3];
    float* out = (float*)d_out;
    unsigned short* bp = (unsigned short*)d_ws;            // 57,344 B
    float* corrf = (float*)((char*)d_ws + 57344);          // 4,096 B

    lu_prep_kernel<<<64, 64, 0, stream>>>(iw, ck, x, bp, corrf);
    lu_main_kernel<<<2048, 256, 0, stream>>>(x, bp, corrf, bias, out);
}